// Round 15
// baseline (143.987 us; speedup 1.0000x reference)
//
#include <hip/hip_runtime.h>

// DAG MLP: L=8 layers, D=64, B=262144, 28 all-to-all forward connections.
// outs[j] += relu(outs[i] @ W_c^T + b_c), output = outs[7].
// v15: RINGLESS. W delivered straight to VGPRs from a FRAGMENT-ORDERED,
// sigma-consistent bf16 image in d_ws (lane's 16B MFMA fragment contiguous;
// global_load_dwordx4 = 1KB coalesced stream; L1 dedups the 2 same-h waves).
//   - 16-row pairs (afrag 56 regs), 4 waves/block, 32 rows/block, grid 8192
//   - W ping-pong reg buffer (4x u16x8 per buf), prefetched 1 conn ahead
//   - NO LDS ring, NO global_load_lds, NO __syncthreads in the main loop;
//     LDS = 8KB pair bounce only; 6 lgkm-only barriers per tile (dbuf parity,
//     single barrier per phase -- write->read publish; read-before-rewrite
//     ordered by the next phase's barrier)
//   - sigma k-permutation (v14) baked into image + x-load + bounce: packed
//     cvt_pk b32 bounce writes
//   - MFMA-carried accumulation: C_in=acc; acc=max(D+b,acc)==acc+relu(S+b)

#define DD 64
#define NCONN 28
#define THREADS 256
#define ROWS_PER_BLOCK 32      // 2 pairs * 16 rows
#define MAT_ELEMS 4096         // 64*64
#define FRAG_STRIDE 2048       // u16 per (conn,h): 4 frags * 64 lanes * 8

typedef __bf16 bf16x8 __attribute__((ext_vector_type(8)));
typedef float f32x4 __attribute__((ext_vector_type(4)));
typedef unsigned short u16x8 __attribute__((ext_vector_type(8)));

// c(i->j) = OFFS[i] + (j-i-1); CONN[p] = connection at compute position p.
__device__ constexpr int OFFS[7] = {0, 7, 13, 18, 22, 25, 27};
__device__ constexpr int CONN[28] = {0, 1,7, 2,8,13, 3,9,14,18, 4,10,15,19,22,
                                     5,11,16,20,23,25, 6,12,17,21,24,26,27};

__device__ __forceinline__ unsigned short f2bfu(float f) {
    return __builtin_bit_cast(unsigned short, (__bf16)f);
}

__device__ __forceinline__ f32x4 vmax4(f32x4 a, f32x4 b) {
#if __has_builtin(__builtin_elementwise_max)
    return __builtin_elementwise_max(a, b);
#else
    f32x4 r;
    r[0] = fmaxf(a[0], b[0]); r[1] = fmaxf(a[1], b[1]);
    r[2] = fmaxf(a[2], b[2]); r[3] = fmaxf(a[3], b[3]);
    return r;
#endif
}

// LDS-only barrier: orders bounce writes/reads without touching vmcnt.
__device__ __forceinline__ void lds_barrier() {
    asm volatile("s_waitcnt lgkmcnt(0)" ::: "memory");
    __builtin_amdgcn_s_barrier();
    asm volatile("" ::: "memory");
}

// Fragment-ordered sigma image. Element (c, h, f, lane, e) at
//   ((c*2+h)*4+f)*512 + lane*8 + e    (u16)
// holds W[c][ n = h*32 + (f>>1)*16 + (lane&15) ]
//        [ k = (f&1)*32 + (lane>>4)*4 + (e>>1) + (e&1)*16 ]   (sigma k-order)
__global__ void wconv_kernel(const float* __restrict__ w,
                             unsigned short* __restrict__ o) {
    int i = blockIdx.x * blockDim.x + threadIdx.x;   // one 16B fragment chunk
    if (i >= NCONN * 2 * 4 * 64) return;
    int lane = i & 63;
    int f    = (i >> 6) & 3;
    int h    = (i >> 8) & 1;
    int c    = i >> 9;
    int n  = h * 32 + (f >> 1) * 16 + (lane & 15);
    int k0 = (f & 1) * 32 + (lane >> 4) * 4;
    const float* src = w + c * MAT_ELEMS + n * DD + k0;
    float4 v0 = *reinterpret_cast<const float4*>(src);        // k0..k0+3
    float4 v1 = *reinterpret_cast<const float4*>(src + 16);   // k0+16..+19
    u16x8 d;   // elem e holds k0 + (e>>1) + (e&1)*16
    d[0] = f2bfu(v0.x); d[1] = f2bfu(v1.x); d[2] = f2bfu(v0.y); d[3] = f2bfu(v1.y);
    d[4] = f2bfu(v0.z); d[5] = f2bfu(v1.z); d[6] = f2bfu(v0.w); d[7] = f2bfu(v1.w);
    *reinterpret_cast<u16x8*>(o + (size_t)i * 8) = d;
}

template <bool FRAG>
__global__ __launch_bounds__(THREADS, 4)
void dag_kernel(const float* __restrict__ x,
                const float* __restrict__ Wf,
                const unsigned short* __restrict__ Wfrag,
                const float* __restrict__ bs,
                float* __restrict__ out) {
    __shared__ __align__(16) unsigned short sB[2 * 2 * 1024];   // 8 KB: pair x dbuf x 2KB

    const int tid  = threadIdx.x;
    const int lane = tid & 63;
    const int wv   = tid >> 6;
    const int pair = wv >> 1;     // 0,1
    const int h    = wv & 1;      // feature half
    const int l15  = lane & 15;
    const int kg   = lane >> 4;

    const long rowbase = (long)blockIdx.x * ROWS_PER_BLOCK + pair * 16;

    // ---- x -> afrag[0], sigma k-order (16 rows) ----
    bf16x8 afrag[7][2];   // [src layer][k step]; row l15
    {
        const float* xr = x + (rowbase + l15) * DD;
#pragma unroll
        for (int s = 0; s < 2; ++s) {
            float4 v0 = *reinterpret_cast<const float4*>(xr + s * 32 + kg * 4);
            float4 v1 = *reinterpret_cast<const float4*>(xr + s * 32 + kg * 4 + 16);
            bf16x8 f;
            f[0] = (__bf16)v0.x; f[1] = (__bf16)v1.x; f[2] = (__bf16)v0.y; f[3] = (__bf16)v1.y;
            f[4] = (__bf16)v0.z; f[5] = (__bf16)v1.z; f[6] = (__bf16)v0.w; f[7] = (__bf16)v1.w;
            afrag[0][s] = f;
        }
    }

    // W fragment ping-pong: conn at position p lives in (p&1)?wB:wA.
    u16x8 wA[4], wB[4];
    auto loadW = [&](int p, u16x8* dst) {
        if constexpr (FRAG) {
            const u16x8* bp = reinterpret_cast<const u16x8*>(
                                  Wfrag + (size_t)(CONN[p] * 2 + h) * FRAG_STRIDE) + lane;
#pragma unroll
            for (int f = 0; f < 4; ++f)
                dst[f] = bp[f * 64];                 // 1KB coalesced per frag
        } else {
            // slow correct fallback: per-lane gather from fp32 W
#pragma unroll
            for (int f = 0; f < 4; ++f) {
                const int n  = h * 32 + (f >> 1) * 16 + l15;
                const int k0 = (f & 1) * 32 + kg * 4;
                const float* s = Wf + CONN[p] * MAT_ELEMS + n * DD + k0;
                u16x8 d;
#pragma unroll
                for (int e = 0; e < 8; ++e)
                    d[e] = f2bfu(s[(e >> 1) + (e & 1) * 16]);
                dst[f] = d;
            }
        }
    };

    // Bias ping-pong (2 floats per conn for this wave's 32 features).
    float bA[2], bB[2];
    auto loadBias = [&](int p, float* dst) {
        const float* bp = bs + CONN[p] * DD + h * 32 + l15;
        dst[0] = bp[0]; dst[1] = bp[16];
    };

    loadW(0, wA);
    loadBias(0, bA);

    unsigned short* myPB = sB + pair * 2048;   // [2 bufs][1024 u16] per pair
    f32x4 acc[2];   // [feat tile t]; feature n = h*32 + t*16 + l15, row kg*4+q

#pragma unroll
    for (int j = 1; j <= 7; ++j) {
#pragma unroll
        for (int t = 0; t < 2; ++t) {
            acc[t][0] = 0.f; acc[t][1] = 0.f; acc[t][2] = 0.f; acc[t][3] = 0.f;
        }

#pragma unroll
        for (int i = 0; i < j; ++i) {
            const int p = j * (j - 1) / 2 + i;      // compute position (constexpr)

            // prefetch next conn's W + bias into the other buffers
            if (p + 1 < NCONN) {
                loadW(p + 1, (p & 1) ? wA : wB);
                loadBias(p + 1, (p & 1) ? bA : bB);
            }
            const u16x8* wc = (p & 1) ? wB : wA;
            const float* bv = (p & 1) ? bB : bA;

            __builtin_amdgcn_s_setprio(1);
#pragma unroll
            for (int t = 0; t < 2; ++t) {
                const f32x4 b4 = {bv[t], bv[t], bv[t], bv[t]};
                f32x4 C = acc[t];
                C = __builtin_amdgcn_mfma_f32_16x16x32_bf16(
                        afrag[i][0], __builtin_bit_cast(bf16x8, wc[t * 2 + 0]), C, 0, 0, 0);
                C = __builtin_amdgcn_mfma_f32_16x16x32_bf16(
                        afrag[i][1], __builtin_bit_cast(bf16x8, wc[t * 2 + 1]), C, 0, 0, 0);
                acc[t] = vmax4(C + b4, acc[t]);
            }
            __builtin_amdgcn_s_setprio(0);
        }

        if (j < 7) {
            // Pair bounce into buf[j&1]: sigma-adjacent (n, n+16) pairs pack
            // into one cvt_pk + one b32 write; 4 writes + 2 b128 reads /wave.
            unsigned short* wb = myPB + (j & 1) * 1024;
            const int sp = h * 32 + 2 * l15;        // even slot of the pair
#pragma unroll
            for (int q = 0; q < 4; ++q) {
                const int mr = kg * 4 + q;
                unsigned int pk;
                asm("v_cvt_pk_bf16_f32 %0, %1, %2"
                    : "=v"(pk) : "v"(acc[0][q]), "v"(acc[1][q]));
                *reinterpret_cast<unsigned int*>(
                    &wb[mr * DD + (sp ^ ((mr & 7) << 3))]) = pk;
            }
            lds_barrier();   // pair writes visible (single barrier per phase)
#pragma unroll
            for (int s = 0; s < 2; ++s) {
                u16x8 ra = *reinterpret_cast<const u16x8*>(
                    &wb[l15 * DD + ((s * 32 + kg * 8) ^ ((l15 & 7) << 3))]);
                afrag[j][s] = __builtin_bit_cast(bf16x8, ra);
            }
            // no read-done barrier: next phase writes the OTHER buffer and its
            // own barrier orders the rewrite after these reads.
        } else {
            float* orow = out + rowbase * DD;
#pragma unroll
            for (int t = 0; t < 2; ++t)
#pragma unroll
                for (int q = 0; q < 4; ++q)
                    orow[(kg * 4 + q) * DD + h * 32 + t * 16 + l15] = acc[t][q];
        }
    }
}

extern "C" void kernel_launch(void* const* d_in, const int* in_sizes, int n_in,
                              void* d_out, int out_size, void* d_ws, size_t ws_size,
                              hipStream_t stream) {
    const float* x  = (const float*)d_in[0];
    const float* Ws = (const float*)d_in[1];
    const float* bs = (const float*)d_in[2];
    float* out = (float*)d_out;

    const int nrows = in_sizes[0] / DD;            // 262144
    const int grid  = nrows / ROWS_PER_BLOCK;      // 8192

    const size_t img_bytes = (size_t)NCONN * 2 * FRAG_STRIDE * sizeof(unsigned short);
    if (ws_size >= img_bytes) {
        unsigned short* wimg = (unsigned short*)d_ws;
        const int n = NCONN * 2 * 4 * 64;          // 14336 fragment chunks
        wconv_kernel<<<(n + 255) / 256, 256, 0, stream>>>(Ws, wimg);
        dag_kernel<true><<<grid, THREADS, 0, stream>>>(x, Ws, wimg, bs, out);
    } else {
        dag_kernel<false><<<grid, THREADS, 0, stream>>>(x, Ws, nullptr, bs, out);
    }
}

// Round 16
// 132.531 us; speedup vs baseline: 1.0864x; 1.0864x over previous
//
#include <hip/hip_runtime.h>

// DAG MLP: L=8 layers, D=64, B=262144, 28 all-to-all forward connections.
// outs[j] += relu(outs[i] @ W_c^T + b_c), output = outs[7].
// v16 = v14 (best, 95.5us) scaled to P=3 PAIRS (6 waves, 96 rows/block):
//   gll-staging and barrier costs amortize over 96 rows instead of 64
//   (-33% per row); B-fragment reads/row and per-wave registers unchanged.
//   Tail: grid 2731, last block's pair 2 is exactly OOB -> pair-granular
//   guard (loads clamped to row 0, stores skipped).
// Structure otherwise identical to v14: 32-row pairs, feature-split waves,
// 4-slot LDS ring, pair __syncthreads, pre-swizzled sigma bf16 W image via
// global_load_lds(16B), bias reg ping-pong, sigma-packed cvt_pk b32 bounce
// (double-buffered, no read-done barrier), setprio, MFMA-carried
// accumulation C_in=acc; acc=max(D+b,acc) == acc+relu(S+b).

#define DD 64
#define NCONN 28
#define THREADS 384            // 6 waves = 3 pairs
#define ROWS_PER_BLOCK 96      // 3 pairs * 32 rows
#define NROWS 262144
#define MAT_ELEMS 4096         // 64*64

typedef __bf16 bf16x8 __attribute__((ext_vector_type(8)));
typedef float f32x4 __attribute__((ext_vector_type(4)));
typedef unsigned short u16x8 __attribute__((ext_vector_type(8)));

// c(i->j) = OFFS[i] + (j-i-1); CONN[p] = connection at compute position p
// (phases j=1..7, sources i ascending within phase).
__device__ constexpr int OFFS[7] = {0, 7, 13, 18, 22, 25, 27};
__device__ constexpr int CONN[28] = {0, 1,7, 2,8,13, 3,9,14,18, 4,10,15,19,22,
                                     5,11,16,20,23,25, 6,12,17,21,24,26,27};

__device__ __forceinline__ unsigned short f2bfu(float f) {
    return __builtin_bit_cast(unsigned short, (__bf16)f);
}

__device__ __forceinline__ f32x4 vmax4(f32x4 a, f32x4 b) {
#if __has_builtin(__builtin_elementwise_max)
    return __builtin_elementwise_max(a, b);
#else
    f32x4 r;
    r[0] = fmaxf(a[0], b[0]); r[1] = fmaxf(a[1], b[1]);
    r[2] = fmaxf(a[2], b[2]); r[3] = fmaxf(a[3], b[3]);
    return r;
#endif
}

__device__ __forceinline__ void gll16(const unsigned short* g, unsigned short* l) {
    __builtin_amdgcn_global_load_lds(
        (const __attribute__((address_space(1))) unsigned int*)g,
        (__attribute__((address_space(3))) unsigned int*)l, 16, 0, 0);
}

// LDS-only barrier: drains lgkm (LDS writes visible) but NOT vmcnt.
__device__ __forceinline__ void lds_barrier() {
    asm volatile("s_waitcnt lgkmcnt(0)" ::: "memory");
    __builtin_amdgcn_s_barrier();
    asm volatile("" ::: "memory");
}

// fp32 W -> bf16 image, sigma-PERMUTED and address-swizzled:
//   slot s (0..63) holds feature feat(s) = (s&32) + ((s&31)>>1) + (s&1)*16
//   img[c][n*64 + (s ^ ((n&7)<<3))] = W[c][n][feat(s)]
// A lane-linear global_load_lds copy reproduces this layout in LDS.
__global__ void wconv_kernel(const float* __restrict__ w,
                             unsigned short* __restrict__ o) {
    int i = blockIdx.x * blockDim.x + threadIdx.x;   // one 8-slot chunk each
    if (i >= NCONN * 512) return;
    int conn = i >> 9;
    int within = i & 511;
    int n  = within >> 3;
    int s0 = (within & 7) << 3;                      // slot octet base
    int fb = (s0 & 32) + ((s0 & 31) >> 1);           // feature base
    const float* src = w + conn * MAT_ELEMS + n * DD + fb;
    float4 v0 = *reinterpret_cast<const float4*>(src);        // feats fb..fb+3
    float4 v1 = *reinterpret_cast<const float4*>(src + 16);   // feats fb+16..+19
    u16x8 d;   // slot s0+e holds feature fb + (e>>1) + (e&1)*16
    d[0] = f2bfu(v0.x); d[1] = f2bfu(v1.x); d[2] = f2bfu(v0.y); d[3] = f2bfu(v1.y);
    d[4] = f2bfu(v0.z); d[5] = f2bfu(v1.z); d[6] = f2bfu(v0.w); d[7] = f2bfu(v1.w);
    *reinterpret_cast<u16x8*>(o + conn * MAT_ELEMS + n * DD + (s0 ^ ((n & 7) << 3))) = d;
}

template <bool GLL>
__global__ __launch_bounds__(THREADS, 3)
void dag_kernel(const float* __restrict__ x,
                const float* __restrict__ Wf,
                const unsigned short* __restrict__ Wimg,
                const float* __restrict__ bs,
                float* __restrict__ out) {
    __shared__ __align__(16) unsigned short ring[4 * MAT_ELEMS];    // 32 KB
    __shared__ __align__(16) unsigned short sB[3 * 2 * 2048];       // 24 KB: pair x dbuf
    // total 56 KB

    const int tid  = threadIdx.x;
    const int lane = tid & 63;
    const int wv   = tid >> 6;
    const int pair = wv >> 1;     // 0,1,2
    const int h    = wv & 1;      // feature half
    const int l15  = lane & 15;
    const int kg   = lane >> 4;

    const long rowbase = (long)blockIdx.x * ROWS_PER_BLOCK + pair * 32;
    const bool active  = rowbase < NROWS;      // pair-granular (tail block)
    const long rb      = active ? rowbase : 0;

    // ---- x -> afrag[0], sigma-ordered k slots ----
    bf16x8 afrag[7][2][2];   // [src layer][row tile][k step]
#pragma unroll
    for (int rt = 0; rt < 2; ++rt) {
        const float* xr = x + (rb + rt * 16 + l15) * DD;
#pragma unroll
        for (int s = 0; s < 2; ++s) {
            float4 v0 = *reinterpret_cast<const float4*>(xr + s * 32 + kg * 4);
            float4 v1 = *reinterpret_cast<const float4*>(xr + s * 32 + kg * 4 + 16);
            bf16x8 f;
            f[0] = (__bf16)v0.x; f[1] = (__bf16)v1.x; f[2] = (__bf16)v0.y; f[3] = (__bf16)v1.y;
            f[4] = (__bf16)v0.z; f[5] = (__bf16)v1.z; f[6] = (__bf16)v0.w; f[7] = (__bf16)v1.w;
            afrag[0][rt][s] = f;
        }
    }

    // Bias ping-pong: breg[pair parity][conn in pair][t]; compile-time indices.
    float breg[2][2][2];
    auto loadBias = [&](int p) {
        const float* bp = bs + CONN[p] * DD + h * 32 + l15;
        float* b = breg[(p >> 1) & 1][p & 1];
        b[0] = bp[0]; b[1] = bp[16];
    };

    // Staging: waves 0..3 copy the 8KB matrix (2 x 1KB insts each); waves 4,5 idle.
    auto stage_gll = [&](int p) {
        if (wv < 4) {
            const unsigned short* src = Wimg + CONN[p] * MAT_ELEMS + wv * 512 + lane * 8;
            unsigned short* dst = ring + (p & 3) * MAT_ELEMS + wv * 512;
#pragma unroll
            for (int hh = 0; hh < 2; ++hh)
                gll16(src + hh * 2048, dst + hh * 2048);
        }
    };
    auto stage_direct = [&](int p) {   // fallback: fp32 -> bf16, sigma + swizzle
        const float* wp = Wf + CONN[p] * MAT_ELEMS;
        for (int e0 = tid * 8; e0 < MAT_ELEMS; e0 += THREADS * 8) {
            const int n  = e0 >> 6, s0 = e0 & 63;
            const int fb = (s0 & 32) + ((s0 & 31) >> 1);
            const float* srcp = wp + n * DD + fb;
            float4 a0 = *reinterpret_cast<const float4*>(srcp);
            float4 a1 = *reinterpret_cast<const float4*>(srcp + 16);
            u16x8 d;
            d[0] = f2bfu(a0.x); d[1] = f2bfu(a1.x); d[2] = f2bfu(a0.y); d[3] = f2bfu(a1.y);
            d[4] = f2bfu(a0.z); d[5] = f2bfu(a1.z); d[6] = f2bfu(a0.w); d[7] = f2bfu(a1.w);
            *reinterpret_cast<u16x8*>(ring + (p & 3) * MAT_ELEMS +
                                      n * DD + (s0 ^ ((n & 7) << 3))) = d;
        }
    };

    loadBias(0); loadBias(1);
    if constexpr (GLL) { stage_gll(0); stage_gll(1); }
    __syncthreads();   // prologue loads drained; slots 0,1 ready

    unsigned short* myPB = sB + pair * 4096;   // [2 bufs][2048 u16] per pair
    f32x4 acc[2][2];   // [row tile][feat tile within half]

#pragma unroll
    for (int j = 1; j <= 7; ++j) {
#pragma unroll
        for (int rt = 0; rt < 2; ++rt)
#pragma unroll
            for (int t = 0; t < 2; ++t) {
                acc[rt][t][0] = 0.f; acc[rt][t][1] = 0.f;
                acc[rt][t][2] = 0.f; acc[rt][t][3] = 0.f;
            }

#pragma unroll
        for (int i = 0; i < j; ++i) {
            const int p = j * (j - 1) / 2 + i;      // compute position 0..27

            if constexpr (GLL) {
                // pair schedule: barrier once per even p publishes slots p,p+1
                // (staged 2 conns ago) and the previous phase's bounce writes.
                if ((p & 1) == 0) {
                    if (p > 0) __syncthreads();
                    if (p + 2 < NCONN) { loadBias(p + 2); loadBias(p + 3); }
                    if (p + 2 < NCONN) { stage_gll(p + 2); stage_gll(p + 3); }
                }
            } else {
                __syncthreads();
                stage_direct(p);
                loadBias(p);
                __syncthreads();
            }

            const unsigned short* wsl = ring + (p & 3) * MAT_ELEMS;
            const float* bv = breg[(p >> 1) & 1][p & 1];
            __builtin_amdgcn_s_setprio(1);
#pragma unroll
            for (int t = 0; t < 2; ++t) {
                const int n  = h * 32 + t * 16 + l15;   // this wave's feature
                const int xo = (n & 7) << 3;
                u16x8 rw0 = *reinterpret_cast<const u16x8*>(wsl + n * DD + ((kg * 8) ^ xo));
                u16x8 rw1 = *reinterpret_cast<const u16x8*>(wsl + n * DD + ((32 + kg * 8) ^ xo));
                const f32x4 b4 = {bv[t], bv[t], bv[t], bv[t]};
#pragma unroll
                for (int rt = 0; rt < 2; ++rt) {
                    f32x4 C = acc[rt][t];
                    C = __builtin_amdgcn_mfma_f32_16x16x32_bf16(
                            afrag[i][rt][0], __builtin_bit_cast(bf16x8, rw0), C, 0, 0, 0);
                    C = __builtin_amdgcn_mfma_f32_16x16x32_bf16(
                            afrag[i][rt][1], __builtin_bit_cast(bf16x8, rw1), C, 0, 0, 0);
                    acc[rt][t] = vmax4(C + b4, acc[rt][t]);
                }
            }
            __builtin_amdgcn_s_setprio(0);
        }

        if (j < 7) {
            // Bounce into buf[j&1]: lane's (n, n+16) pair is sigma-adjacent ->
            // one cvt_pk + one b32 write per (rt,q). 8 writes/wave/phase.
            unsigned short* wb = myPB + (j & 1) * 2048;
            const int sp = h * 32 + 2 * l15;            // even slot of the pair
#pragma unroll
            for (int rt = 0; rt < 2; ++rt)
#pragma unroll
                for (int q = 0; q < 4; ++q) {
                    const int mr = rt * 16 + kg * 4 + q;
                    unsigned int pk;
                    asm("v_cvt_pk_bf16_f32 %0, %1, %2"
                        : "=v"(pk) : "v"(acc[rt][0][q]), "v"(acc[rt][1][q]));
                    *reinterpret_cast<unsigned int*>(
                        &wb[mr * DD + (sp ^ ((mr & 7) << 3))]) = pk;
                }
            lds_barrier();   // pair writes visible; vmcnt (glls) NOT drained
#pragma unroll
            for (int rt = 0; rt < 2; ++rt)
#pragma unroll
                for (int s = 0; s < 2; ++s) {
                    u16x8 ra = *reinterpret_cast<const u16x8*>(
                        &wb[(rt * 16 + l15) * DD + ((s * 32 + kg * 8) ^ ((l15 & 7) << 3))]);
                    afrag[j][rt][s] = __builtin_bit_cast(bf16x8, ra);
                }
            // no read-done barrier: next phase writes the OTHER buffer, and
            // its first __syncthreads orders the buffer swap across waves.
        } else if (active) {
            float* orow = out + rowbase * DD;
#pragma unroll
            for (int rt = 0; rt < 2; ++rt)
#pragma unroll
                for (int t = 0; t < 2; ++t)
#pragma unroll
                    for (int q = 0; q < 4; ++q)
                        orow[(rt * 16 + kg * 4 + q) * DD + h * 32 + t * 16 + l15] =
                            acc[rt][t][q];
        }
    }
}

extern "C" void kernel_launch(void* const* d_in, const int* in_sizes, int n_in,
                              void* d_out, int out_size, void* d_ws, size_t ws_size,
                              hipStream_t stream) {
    const float* x  = (const float*)d_in[0];
    const float* Ws = (const float*)d_in[1];
    const float* bs = (const float*)d_in[2];
    float* out = (float*)d_out;

    const int nrows = in_sizes[0] / DD;                       // 262144
    const int grid  = (nrows + ROWS_PER_BLOCK - 1) / ROWS_PER_BLOCK;   // 2731

    const size_t wbf_bytes = (size_t)NCONN * MAT_ELEMS * sizeof(unsigned short);
    if (ws_size >= wbf_bytes) {
        unsigned short* wbf = (unsigned short*)d_ws;
        wconv_kernel<<<(NCONN * 512 + 255) / 256, 256, 0, stream>>>(Ws, wbf);
        dag_kernel<true><<<grid, THREADS, 0, stream>>>(x, Ws, wbf, bs, out);
    } else {
        dag_kernel<false><<<grid, THREADS, 0, stream>>>(x, Ws, nullptr, bs, out);
    }
}

// Round 17
// 101.970 us; speedup vs baseline: 1.4121x; 1.2997x over previous
//
#include <hip/hip_runtime.h>

// DAG MLP: L=8 layers, D=64, B=262144, 28 all-to-all forward connections.
// outs[j] += relu(outs[i] @ W_c^T + b_c), output = outs[7].
// v17 = v14 (best, 95.5us) MINUS s_setprio (A/B: m190 evidence setprio hurts
// barrier-synced lockstep structures; v14's pair-barrier loop is one).
// Everything else byte-identical to v14:
//   - 2 pairs x 32 rows, feature-split waves, 4-slot LDS ring, pair
//     __syncthreads, pre-swizzled sigma bf16 W image via global_load_lds(16B)
//   - bias in register ping-pong
//   - sigma k-permutation baked into W image + x-load: bounce writes are
//     8x {v_cvt_pk_bf16_f32 + ds_write_b32} per wave per phase
//   - bounce double-buffered by phase parity; no read-done barrier
//   - MFMA-carried accumulation C_in=acc; acc=max(D+b,acc)==acc+relu(S+b)

#define DD 64
#define NCONN 28
#define THREADS 256
#define ROWS_PER_BLOCK 64      // 2 pairs * 32 rows
#define MAT_ELEMS 4096         // 64*64

typedef __bf16 bf16x8 __attribute__((ext_vector_type(8)));
typedef float f32x4 __attribute__((ext_vector_type(4)));
typedef unsigned short u16x8 __attribute__((ext_vector_type(8)));

// c(i->j) = OFFS[i] + (j-i-1); CONN[p] = connection at compute position p
// (phases j=1..7, sources i ascending within phase).
__device__ constexpr int OFFS[7] = {0, 7, 13, 18, 22, 25, 27};
__device__ constexpr int CONN[28] = {0, 1,7, 2,8,13, 3,9,14,18, 4,10,15,19,22,
                                     5,11,16,20,23,25, 6,12,17,21,24,26,27};

__device__ __forceinline__ unsigned short f2bfu(float f) {
    return __builtin_bit_cast(unsigned short, (__bf16)f);
}

__device__ __forceinline__ f32x4 vmax4(f32x4 a, f32x4 b) {
#if __has_builtin(__builtin_elementwise_max)
    return __builtin_elementwise_max(a, b);
#else
    f32x4 r;
    r[0] = fmaxf(a[0], b[0]); r[1] = fmaxf(a[1], b[1]);
    r[2] = fmaxf(a[2], b[2]); r[3] = fmaxf(a[3], b[3]);
    return r;
#endif
}

__device__ __forceinline__ void gll16(const unsigned short* g, unsigned short* l) {
    __builtin_amdgcn_global_load_lds(
        (const __attribute__((address_space(1))) unsigned int*)g,
        (__attribute__((address_space(3))) unsigned int*)l, 16, 0, 0);
}

// LDS-only barrier: drains lgkm (LDS writes visible) but NOT vmcnt.
__device__ __forceinline__ void lds_barrier() {
    asm volatile("s_waitcnt lgkmcnt(0)" ::: "memory");
    __builtin_amdgcn_s_barrier();
    asm volatile("" ::: "memory");
}

// fp32 W -> bf16 image, sigma-PERMUTED and address-swizzled:
//   slot s (0..63) holds feature feat(s) = (s&32) + ((s&31)>>1) + (s&1)*16
//   img[c][n*64 + (s ^ ((n&7)<<3))] = W[c][n][feat(s)]
// A lane-linear global_load_lds copy reproduces this layout in LDS.
__global__ void wconv_kernel(const float* __restrict__ w,
                             unsigned short* __restrict__ o) {
    int i = blockIdx.x * blockDim.x + threadIdx.x;   // one 8-slot chunk each
    if (i >= NCONN * 512) return;
    int conn = i >> 9;
    int within = i & 511;
    int n  = within >> 3;
    int s0 = (within & 7) << 3;                      // slot octet base
    int fb = (s0 & 32) + ((s0 & 31) >> 1);           // feature base
    const float* src = w + conn * MAT_ELEMS + n * DD + fb;
    float4 v0 = *reinterpret_cast<const float4*>(src);        // feats fb..fb+3
    float4 v1 = *reinterpret_cast<const float4*>(src + 16);   // feats fb+16..+19
    u16x8 d;   // slot s0+e holds feature fb + (e>>1) + (e&1)*16
    d[0] = f2bfu(v0.x); d[1] = f2bfu(v1.x); d[2] = f2bfu(v0.y); d[3] = f2bfu(v1.y);
    d[4] = f2bfu(v0.z); d[5] = f2bfu(v1.z); d[6] = f2bfu(v0.w); d[7] = f2bfu(v1.w);
    *reinterpret_cast<u16x8*>(o + conn * MAT_ELEMS + n * DD + (s0 ^ ((n & 7) << 3))) = d;
}

template <bool GLL>
__global__ __launch_bounds__(THREADS, 3)
void dag_kernel(const float* __restrict__ x,
                const float* __restrict__ Wf,
                const unsigned short* __restrict__ Wimg,
                const float* __restrict__ bs,
                float* __restrict__ out) {
    __shared__ __align__(16) unsigned short ring[4 * MAT_ELEMS];    // 32 KB
    __shared__ __align__(16) unsigned short sB[2 * 2 * 2048];       // 16 KB: pair x dbuf
    // total 48 KB -> 3 blocks/CU

    const int tid  = threadIdx.x;
    const int lane = tid & 63;
    const int wv   = tid >> 6;
    const int pair = wv >> 1;     // 0,1
    const int h    = wv & 1;      // feature half
    const int l15  = lane & 15;
    const int kg   = lane >> 4;

    const long rowbase = (long)blockIdx.x * ROWS_PER_BLOCK + pair * 32;

    // ---- x -> afrag[0], sigma-ordered k slots ----
    // slot kg*8+e (within kstep s) = feature s*32 + kg*4 + (e>>1) + (e&1)*16
    bf16x8 afrag[7][2][2];   // [src layer][row tile][k step]
#pragma unroll
    for (int rt = 0; rt < 2; ++rt) {
        const float* xr = x + (rowbase + rt * 16 + l15) * DD;
#pragma unroll
        for (int s = 0; s < 2; ++s) {
            float4 v0 = *reinterpret_cast<const float4*>(xr + s * 32 + kg * 4);
            float4 v1 = *reinterpret_cast<const float4*>(xr + s * 32 + kg * 4 + 16);
            bf16x8 f;
            f[0] = (__bf16)v0.x; f[1] = (__bf16)v1.x; f[2] = (__bf16)v0.y; f[3] = (__bf16)v1.y;
            f[4] = (__bf16)v0.z; f[5] = (__bf16)v1.z; f[6] = (__bf16)v0.w; f[7] = (__bf16)v1.w;
            afrag[0][rt][s] = f;
        }
    }

    // Bias ping-pong: breg[pair parity][conn in pair][t]; compile-time indices.
    float breg[2][2][2];
    auto loadBias = [&](int p) {
        const float* bp = bs + CONN[p] * DD + h * 32 + l15;
        float* b = breg[(p >> 1) & 1][p & 1];
        b[0] = bp[0]; b[1] = bp[16];
    };

    auto stage_gll = [&](int p) {
        const unsigned short* src = Wimg + CONN[p] * MAT_ELEMS + wv * 512 + lane * 8;
        unsigned short* dst = ring + (p & 3) * MAT_ELEMS + wv * 512;
#pragma unroll
        for (int hh = 0; hh < 2; ++hh)
            gll16(src + hh * 2048, dst + hh * 2048);
    };
    auto stage_direct = [&](int p) {   // fallback: fp32 -> bf16, sigma + swizzle
        const float* wp = Wf + CONN[p] * MAT_ELEMS;
#pragma unroll
        for (int hh = 0; hh < 2; ++hh) {
            const int e0 = hh * 2048 + tid * 8;      // linear u16 index = n*64 + s0
            const int n  = e0 >> 6, s0 = e0 & 63;
            const int fb = (s0 & 32) + ((s0 & 31) >> 1);
            const float* srcp = wp + n * DD + fb;
            float4 a0 = *reinterpret_cast<const float4*>(srcp);
            float4 a1 = *reinterpret_cast<const float4*>(srcp + 16);
            u16x8 d;
            d[0] = f2bfu(a0.x); d[1] = f2bfu(a1.x); d[2] = f2bfu(a0.y); d[3] = f2bfu(a1.y);
            d[4] = f2bfu(a0.z); d[5] = f2bfu(a1.z); d[6] = f2bfu(a0.w); d[7] = f2bfu(a1.w);
            *reinterpret_cast<u16x8*>(ring + (p & 3) * MAT_ELEMS +
                                      n * DD + (s0 ^ ((n & 7) << 3))) = d;
        }
    };

    loadBias(0); loadBias(1);
    if constexpr (GLL) { stage_gll(0); stage_gll(1); }
    __syncthreads();   // prologue loads drained; slots 0,1 ready

    unsigned short* myPB = sB + pair * 4096;   // [2 bufs][2048 u16] per pair
    f32x4 acc[2][2];   // [row tile][feat tile within half]

#pragma unroll
    for (int j = 1; j <= 7; ++j) {
#pragma unroll
        for (int rt = 0; rt < 2; ++rt)
#pragma unroll
            for (int t = 0; t < 2; ++t) {
                acc[rt][t][0] = 0.f; acc[rt][t][1] = 0.f;
                acc[rt][t][2] = 0.f; acc[rt][t][3] = 0.f;
            }

#pragma unroll
        for (int i = 0; i < j; ++i) {
            const int p = j * (j - 1) / 2 + i;      // compute position 0..27

            if constexpr (GLL) {
                // pair schedule: barrier once per even p publishes slots p,p+1
                // (staged 2 conns ago) and the previous phase's bounce writes.
                if ((p & 1) == 0) {
                    if (p > 0) __syncthreads();
                    if (p + 2 < NCONN) { loadBias(p + 2); loadBias(p + 3); }
                    if (p + 2 < NCONN) { stage_gll(p + 2); stage_gll(p + 3); }
                }
            } else {
                __syncthreads();
                stage_direct(p);
                loadBias(p);
                __syncthreads();
            }

            const unsigned short* wsl = ring + (p & 3) * MAT_ELEMS;
            const float* bv = breg[(p >> 1) & 1][p & 1];
#pragma unroll
            for (int t = 0; t < 2; ++t) {
                const int n  = h * 32 + t * 16 + l15;   // this wave's feature
                const int xo = (n & 7) << 3;
                u16x8 rw0 = *reinterpret_cast<const u16x8*>(wsl + n * DD + ((kg * 8) ^ xo));
                u16x8 rw1 = *reinterpret_cast<const u16x8*>(wsl + n * DD + ((32 + kg * 8) ^ xo));
                const f32x4 b4 = {bv[t], bv[t], bv[t], bv[t]};
#pragma unroll
                for (int rt = 0; rt < 2; ++rt) {
                    f32x4 C = acc[rt][t];
                    C = __builtin_amdgcn_mfma_f32_16x16x32_bf16(
                            afrag[i][rt][0], __builtin_bit_cast(bf16x8, rw0), C, 0, 0, 0);
                    C = __builtin_amdgcn_mfma_f32_16x16x32_bf16(
                            afrag[i][rt][1], __builtin_bit_cast(bf16x8, rw1), C, 0, 0, 0);
                    acc[rt][t] = vmax4(C + b4, acc[rt][t]);
                }
            }
        }

        if (j < 7) {
            // Bounce into buf[j&1]: lane's (n, n+16) pair is sigma-adjacent ->
            // one cvt_pk + one b32 write per (rt,q). 8 writes/wave/phase.
            unsigned short* wb = myPB + (j & 1) * 2048;
            const int sp = h * 32 + 2 * l15;            // even slot of the pair
#pragma unroll
            for (int rt = 0; rt < 2; ++rt)
#pragma unroll
                for (int q = 0; q < 4; ++q) {
                    const int mr = rt * 16 + kg * 4 + q;
                    unsigned int pk;
                    asm("v_cvt_pk_bf16_f32 %0, %1, %2"
                        : "=v"(pk) : "v"(acc[rt][0][q]), "v"(acc[rt][1][q]));
                    *reinterpret_cast<unsigned int*>(
                        &wb[mr * DD + (sp ^ ((mr & 7) << 3))]) = pk;
                }
            lds_barrier();   // pair writes visible; vmcnt (glls) NOT drained
#pragma unroll
            for (int rt = 0; rt < 2; ++rt)
#pragma unroll
                for (int s = 0; s < 2; ++s) {
                    u16x8 ra = *reinterpret_cast<const u16x8*>(
                        &wb[(rt * 16 + l15) * DD + ((s * 32 + kg * 8) ^ ((l15 & 7) << 3))]);
                    afrag[j][rt][s] = __builtin_bit_cast(bf16x8, ra);
                }
            // no read-done barrier: next phase writes the OTHER buffer, and
            // its first __syncthreads orders the buffer swap across waves.
        } else {
            float* orow = out + rowbase * DD;
#pragma unroll
            for (int rt = 0; rt < 2; ++rt)
#pragma unroll
                for (int t = 0; t < 2; ++t)
#pragma unroll
                    for (int q = 0; q < 4; ++q)
                        orow[(rt * 16 + kg * 4 + q) * DD + h * 32 + t * 16 + l15] =
                            acc[rt][t][q];
        }
    }
}

extern "C" void kernel_launch(void* const* d_in, const int* in_sizes, int n_in,
                              void* d_out, int out_size, void* d_ws, size_t ws_size,
                              hipStream_t stream) {
    const float* x  = (const float*)d_in[0];
    const float* Ws = (const float*)d_in[1];
    const float* bs = (const float*)d_in[2];
    float* out = (float*)d_out;

    const int nrows = in_sizes[0] / DD;            // 262144
    const int grid  = nrows / ROWS_PER_BLOCK;      // 4096

    const size_t wbf_bytes = (size_t)NCONN * MAT_ELEMS * sizeof(unsigned short);
    if (ws_size >= wbf_bytes) {
        unsigned short* wbf = (unsigned short*)d_ws;
        wconv_kernel<<<(NCONN * 512 + 255) / 256, 256, 0, stream>>>(Ws, wbf);
        dag_kernel<true><<<grid, THREADS, 0, stream>>>(x, Ws, wbf, bs, out);
    } else {
        dag_kernel<false><<<grid, THREADS, 0, stream>>>(x, Ws, nullptr, bs, out);
    }
}

// Round 18
// 95.704 us; speedup vs baseline: 1.5045x; 1.0655x over previous
//
#include <hip/hip_runtime.h>

// DAG MLP: L=8 layers, D=64, B=262144, 28 all-to-all forward connections.
// outs[j] += relu(outs[i] @ W_c^T + b_c), output = outs[7].
// FINAL = v14 (session best, 95.5us), restored byte-identical after the v17
// A/B proved s_setprio is worth +6.5% here (and its removal perturbs codegen
// into scratch spill: WRITE 65.5->89.7 MB).
// Design (each element bracketed by a measured failure of its alternative):
//   - 2 pairs x 32 rows/wave, feature-split waves (v8)
//   - 4-slot LDS ring, pair __syncthreads, global_load_lds(16B) from a
//     pre-swizzled sigma bf16 W image in d_ws (v5/v8)
//   - bias in register ping-pong, loaded before glls (v7/v14)
//   - sigma k-permutation baked into W image + x-load: bounce writes are
//     8x {v_cvt_pk_bf16_f32 + ds_write_b32} per wave per phase (v14)
//   - bounce double-buffered by phase parity; no read-done barrier (v14)
//   - MFMA-carried accumulation C_in=acc; acc=max(D+b,acc)==acc+relu(S+b) (v5)
//   - s_setprio(1) around the MFMA cluster (v17 A/B: required)

#define DD 64
#define NCONN 28
#define THREADS 256
#define ROWS_PER_BLOCK 64      // 2 pairs * 32 rows
#define MAT_ELEMS 4096         // 64*64

typedef __bf16 bf16x8 __attribute__((ext_vector_type(8)));
typedef float f32x4 __attribute__((ext_vector_type(4)));
typedef unsigned short u16x8 __attribute__((ext_vector_type(8)));

// c(i->j) = OFFS[i] + (j-i-1); CONN[p] = connection at compute position p
// (phases j=1..7, sources i ascending within phase).
__device__ constexpr int OFFS[7] = {0, 7, 13, 18, 22, 25, 27};
__device__ constexpr int CONN[28] = {0, 1,7, 2,8,13, 3,9,14,18, 4,10,15,19,22,
                                     5,11,16,20,23,25, 6,12,17,21,24,26,27};

__device__ __forceinline__ unsigned short f2bfu(float f) {
    return __builtin_bit_cast(unsigned short, (__bf16)f);
}

__device__ __forceinline__ f32x4 vmax4(f32x4 a, f32x4 b) {
#if __has_builtin(__builtin_elementwise_max)
    return __builtin_elementwise_max(a, b);
#else
    f32x4 r;
    r[0] = fmaxf(a[0], b[0]); r[1] = fmaxf(a[1], b[1]);
    r[2] = fmaxf(a[2], b[2]); r[3] = fmaxf(a[3], b[3]);
    return r;
#endif
}

__device__ __forceinline__ void gll16(const unsigned short* g, unsigned short* l) {
    __builtin_amdgcn_global_load_lds(
        (const __attribute__((address_space(1))) unsigned int*)g,
        (__attribute__((address_space(3))) unsigned int*)l, 16, 0, 0);
}

// LDS-only barrier: drains lgkm (LDS writes visible) but NOT vmcnt.
__device__ __forceinline__ void lds_barrier() {
    asm volatile("s_waitcnt lgkmcnt(0)" ::: "memory");
    __builtin_amdgcn_s_barrier();
    asm volatile("" ::: "memory");
}

// fp32 W -> bf16 image, sigma-PERMUTED and address-swizzled:
//   slot s (0..63) holds feature feat(s) = (s&32) + ((s&31)>>1) + (s&1)*16
//   img[c][n*64 + (s ^ ((n&7)<<3))] = W[c][n][feat(s)]
// A lane-linear global_load_lds copy reproduces this layout in LDS.
__global__ void wconv_kernel(const float* __restrict__ w,
                             unsigned short* __restrict__ o) {
    int i = blockIdx.x * blockDim.x + threadIdx.x;   // one 8-slot chunk each
    if (i >= NCONN * 512) return;
    int conn = i >> 9;
    int within = i & 511;
    int n  = within >> 3;
    int s0 = (within & 7) << 3;                      // slot octet base
    int fb = (s0 & 32) + ((s0 & 31) >> 1);           // feature base
    const float* src = w + conn * MAT_ELEMS + n * DD + fb;
    float4 v0 = *reinterpret_cast<const float4*>(src);        // feats fb..fb+3
    float4 v1 = *reinterpret_cast<const float4*>(src + 16);   // feats fb+16..+19
    u16x8 d;   // slot s0+e holds feature fb + (e>>1) + (e&1)*16
    d[0] = f2bfu(v0.x); d[1] = f2bfu(v1.x); d[2] = f2bfu(v0.y); d[3] = f2bfu(v1.y);
    d[4] = f2bfu(v0.z); d[5] = f2bfu(v1.z); d[6] = f2bfu(v0.w); d[7] = f2bfu(v1.w);
    *reinterpret_cast<u16x8*>(o + conn * MAT_ELEMS + n * DD + (s0 ^ ((n & 7) << 3))) = d;
}

template <bool GLL>
__global__ __launch_bounds__(THREADS, 3)
void dag_kernel(const float* __restrict__ x,
                const float* __restrict__ Wf,
                const unsigned short* __restrict__ Wimg,
                const float* __restrict__ bs,
                float* __restrict__ out) {
    __shared__ __align__(16) unsigned short ring[4 * MAT_ELEMS];    // 32 KB
    __shared__ __align__(16) unsigned short sB[2 * 2 * 2048];       // 16 KB: pair x dbuf
    // total 48 KB -> 3 blocks/CU

    const int tid  = threadIdx.x;
    const int lane = tid & 63;
    const int wv   = tid >> 6;
    const int pair = wv >> 1;     // 0,1
    const int h    = wv & 1;      // feature half
    const int l15  = lane & 15;
    const int kg   = lane >> 4;

    const long rowbase = (long)blockIdx.x * ROWS_PER_BLOCK + pair * 32;

    // ---- x -> afrag[0], sigma-ordered k slots ----
    // slot kg*8+e (within kstep s) = feature s*32 + kg*4 + (e>>1) + (e&1)*16
    bf16x8 afrag[7][2][2];   // [src layer][row tile][k step]
#pragma unroll
    for (int rt = 0; rt < 2; ++rt) {
        const float* xr = x + (rowbase + rt * 16 + l15) * DD;
#pragma unroll
        for (int s = 0; s < 2; ++s) {
            float4 v0 = *reinterpret_cast<const float4*>(xr + s * 32 + kg * 4);
            float4 v1 = *reinterpret_cast<const float4*>(xr + s * 32 + kg * 4 + 16);
            bf16x8 f;
            f[0] = (__bf16)v0.x; f[1] = (__bf16)v1.x; f[2] = (__bf16)v0.y; f[3] = (__bf16)v1.y;
            f[4] = (__bf16)v0.z; f[5] = (__bf16)v1.z; f[6] = (__bf16)v0.w; f[7] = (__bf16)v1.w;
            afrag[0][rt][s] = f;
        }
    }

    // Bias ping-pong: breg[pair parity][conn in pair][t]; compile-time indices.
    float breg[2][2][2];
    auto loadBias = [&](int p) {
        const float* bp = bs + CONN[p] * DD + h * 32 + l15;
        float* b = breg[(p >> 1) & 1][p & 1];
        b[0] = bp[0]; b[1] = bp[16];
    };

    auto stage_gll = [&](int p) {
        const unsigned short* src = Wimg + CONN[p] * MAT_ELEMS + wv * 512 + lane * 8;
        unsigned short* dst = ring + (p & 3) * MAT_ELEMS + wv * 512;
#pragma unroll
        for (int hh = 0; hh < 2; ++hh)
            gll16(src + hh * 2048, dst + hh * 2048);
    };
    auto stage_direct = [&](int p) {   // fallback: fp32 -> bf16, sigma + swizzle
        const float* wp = Wf + CONN[p] * MAT_ELEMS;
#pragma unroll
        for (int hh = 0; hh < 2; ++hh) {
            const int e0 = hh * 2048 + tid * 8;      // linear u16 index = n*64 + s0
            const int n  = e0 >> 6, s0 = e0 & 63;
            const int fb = (s0 & 32) + ((s0 & 31) >> 1);
            const float* srcp = wp + n * DD + fb;
            float4 a0 = *reinterpret_cast<const float4*>(srcp);
            float4 a1 = *reinterpret_cast<const float4*>(srcp + 16);
            u16x8 d;
            d[0] = f2bfu(a0.x); d[1] = f2bfu(a1.x); d[2] = f2bfu(a0.y); d[3] = f2bfu(a1.y);
            d[4] = f2bfu(a0.z); d[5] = f2bfu(a1.z); d[6] = f2bfu(a0.w); d[7] = f2bfu(a1.w);
            *reinterpret_cast<u16x8*>(ring + (p & 3) * MAT_ELEMS +
                                      n * DD + (s0 ^ ((n & 7) << 3))) = d;
        }
    };

    loadBias(0); loadBias(1);
    if constexpr (GLL) { stage_gll(0); stage_gll(1); }
    __syncthreads();   // prologue loads drained; slots 0,1 ready

    unsigned short* myPB = sB + pair * 4096;   // [2 bufs][2048 u16] per pair
    f32x4 acc[2][2];   // [row tile][feat tile within half]

#pragma unroll
    for (int j = 1; j <= 7; ++j) {
#pragma unroll
        for (int rt = 0; rt < 2; ++rt)
#pragma unroll
            for (int t = 0; t < 2; ++t) {
                acc[rt][t][0] = 0.f; acc[rt][t][1] = 0.f;
                acc[rt][t][2] = 0.f; acc[rt][t][3] = 0.f;
            }

#pragma unroll
        for (int i = 0; i < j; ++i) {
            const int p = j * (j - 1) / 2 + i;      // compute position 0..27

            if constexpr (GLL) {
                // pair schedule: barrier once per even p publishes slots p,p+1
                // (staged 2 conns ago) and the previous phase's bounce writes.
                if ((p & 1) == 0) {
                    if (p > 0) __syncthreads();
                    if (p + 2 < NCONN) { loadBias(p + 2); loadBias(p + 3); }
                    if (p + 2 < NCONN) { stage_gll(p + 2); stage_gll(p + 3); }
                }
            } else {
                __syncthreads();
                stage_direct(p);
                loadBias(p);
                __syncthreads();
            }

            const unsigned short* wsl = ring + (p & 3) * MAT_ELEMS;
            const float* bv = breg[(p >> 1) & 1][p & 1];
            __builtin_amdgcn_s_setprio(1);
#pragma unroll
            for (int t = 0; t < 2; ++t) {
                const int n  = h * 32 + t * 16 + l15;   // this wave's feature
                const int xo = (n & 7) << 3;
                u16x8 rw0 = *reinterpret_cast<const u16x8*>(wsl + n * DD + ((kg * 8) ^ xo));
                u16x8 rw1 = *reinterpret_cast<const u16x8*>(wsl + n * DD + ((32 + kg * 8) ^ xo));
                const f32x4 b4 = {bv[t], bv[t], bv[t], bv[t]};
#pragma unroll
                for (int rt = 0; rt < 2; ++rt) {
                    f32x4 C = acc[rt][t];
                    C = __builtin_amdgcn_mfma_f32_16x16x32_bf16(
                            afrag[i][rt][0], __builtin_bit_cast(bf16x8, rw0), C, 0, 0, 0);
                    C = __builtin_amdgcn_mfma_f32_16x16x32_bf16(
                            afrag[i][rt][1], __builtin_bit_cast(bf16x8, rw1), C, 0, 0, 0);
                    acc[rt][t] = vmax4(C + b4, acc[rt][t]);
                }
            }
            __builtin_amdgcn_s_setprio(0);
        }

        if (j < 7) {
            // Bounce into buf[j&1]: lane's (n, n+16) pair is sigma-adjacent ->
            // one cvt_pk + one b32 write per (rt,q). 8 writes/wave/phase.
            unsigned short* wb = myPB + (j & 1) * 2048;
            const int sp = h * 32 + 2 * l15;            // even slot of the pair
#pragma unroll
            for (int rt = 0; rt < 2; ++rt)
#pragma unroll
                for (int q = 0; q < 4; ++q) {
                    const int mr = rt * 16 + kg * 4 + q;
                    unsigned int pk;
                    asm("v_cvt_pk_bf16_f32 %0, %1, %2"
                        : "=v"(pk) : "v"(acc[rt][0][q]), "v"(acc[rt][1][q]));
                    *reinterpret_cast<unsigned int*>(
                        &wb[mr * DD + (sp ^ ((mr & 7) << 3))]) = pk;
                }
            lds_barrier();   // pair writes visible; vmcnt (glls) NOT drained
#pragma unroll
            for (int rt = 0; rt < 2; ++rt)
#pragma unroll
                for (int s = 0; s < 2; ++s) {
                    u16x8 ra = *reinterpret_cast<const u16x8*>(
                        &wb[(rt * 16 + l15) * DD + ((s * 32 + kg * 8) ^ ((l15 & 7) << 3))]);
                    afrag[j][rt][s] = __builtin_bit_cast(bf16x8, ra);
                }
            // no read-done barrier: next phase writes the OTHER buffer, and
            // its first __syncthreads orders the buffer swap across waves.
        } else {
            float* orow = out + rowbase * DD;
#pragma unroll
            for (int rt = 0; rt < 2; ++rt)
#pragma unroll
                for (int t = 0; t < 2; ++t)
#pragma unroll
                    for (int q = 0; q < 4; ++q)
                        orow[(rt * 16 + kg * 4 + q) * DD + h * 32 + t * 16 + l15] =
                            acc[rt][t][q];
        }
    }
}

extern "C" void kernel_launch(void* const* d_in, const int* in_sizes, int n_in,
                              void* d_out, int out_size, void* d_ws, size_t ws_size,
                              hipStream_t stream) {
    const float* x  = (const float*)d_in[0];
    const float* Ws = (const float*)d_in[1];
    const float* bs = (const float*)d_in[2];
    float* out = (float*)d_out;

    const int nrows = in_sizes[0] / DD;            // 262144
    const int grid  = nrows / ROWS_PER_BLOCK;      // 4096

    const size_t wbf_bytes = (size_t)NCONN * MAT_ELEMS * sizeof(unsigned short);
    if (ws_size >= wbf_bytes) {
        unsigned short* wbf = (unsigned short*)d_ws;
        wconv_kernel<<<(NCONN * 512 + 255) / 256, 256, 0, stream>>>(Ws, wbf);
        dag_kernel<true><<<grid, THREADS, 0, stream>>>(x, Ws, wbf, bs, out);
    } else {
        dag_kernel<false><<<grid, THREADS, 0, stream>>>(x, Ws, nullptr, bs, out);
    }
}